// Round 6
// baseline (41.403 us; speedup 1.0000x reference)
//
#include <hip/hip_runtime.h>

// SkeLossMultiClass: streaming reduction, two kernels (partial + final).
// B=2, C=4, D=64, H=256, W=256; classes 1..3; BETA=25, EPS=1e-4.
// Per element, per class c: ev=(v==c), es=(s==c)
//   num_c  += p_c * ev * (0.1+es)
//   den1_c += p_c * (1.1 - ev + es)
//   den2_c += ev * (0.1+es)
// score = (26*num+eps)/(den1+25*den2+eps); loss = -mean_b(sum_c score/3)
// Channel 0 of probs never read (33 MB saved). Ignore-mask is a provable no-op.
// R4 lesson: NO __threadfence() on the hot path (per-thread fences -> 242 us).
// R5 lesson: contiguous chunks per stream beat 4MB-strided by ~4 us.
// R6: double chunk to 32 KB/stream/block (TPB=512, GX=512, same VGPR shape).

#define DHW (64 * 256 * 256)   // 4194304
#define NVEC (DHW / 4)         // 1048576 float4/int4 per (b,c)
#define GX 512
#define TPB 512
#define NITER 4
#define CHUNK (TPB * NITER)    // 2048 float4s: contiguous 32 KB per stream/block
#define NACC 9                 // num[3], den1[3], den2[3]
#define FTPB 256               // final kernel block size

__global__ __launch_bounds__(TPB) void ske_partial_kernel(
    const float* __restrict__ out, const int* __restrict__ labels,
    float* __restrict__ ws)
{
    const int b = blockIdx.y;
    const int bx = blockIdx.x;
    const float4* p1 = (const float4*)(out + ((size_t)(b * 4 + 1)) * DHW);
    const float4* p2 = (const float4*)(out + ((size_t)(b * 4 + 2)) * DHW);
    const float4* p3 = (const float4*)(out + ((size_t)(b * 4 + 3)) * DHW);
    const int4* ves = (const int4*)(labels + (size_t)(b * 2) * DHW);
    const int4* ske = ves + NVEC;

    // Contiguous 32 KB per stream per block; 20 independent loads up-front.
    const int base = bx * CHUNK + threadIdx.x;

    float4 A1[NITER], A2[NITER], A3[NITER];
    int4 V[NITER], S[NITER];
#pragma unroll
    for (int q = 0; q < NITER; ++q) {
        const int i = base + q * TPB;
        A1[q] = p1[i];
        A2[q] = p2[i];
        A3[q] = p3[i];
        V[q] = ves[i];
        S[q] = ske[i];
    }

    float num[3] = {0.f, 0.f, 0.f};
    float d1[3]  = {0.f, 0.f, 0.f};
    float d2[3]  = {0.f, 0.f, 0.f};

#pragma unroll
    for (int q = 0; q < NITER; ++q) {
        const float pv[4][3] = {{A1[q].x, A2[q].x, A3[q].x},
                                {A1[q].y, A2[q].y, A3[q].y},
                                {A1[q].z, A2[q].z, A3[q].z},
                                {A1[q].w, A2[q].w, A3[q].w}};
        const int vv[4] = {V[q].x, V[q].y, V[q].z, V[q].w};
        const int sv[4] = {S[q].x, S[q].y, S[q].z, S[q].w};
#pragma unroll
        for (int j = 0; j < 4; ++j) {
#pragma unroll
            for (int c = 0; c < 3; ++c) {
                const bool mv = (vv[j] == c + 1);
                const bool ms = (sv[j] == c + 1);
                const float t   = ms ? 1.1f : 0.1f;      // 0.1 + es
                const float w   = mv ? t : 0.0f;         // ev*(0.1+es)
                const float imp = mv ? t : (t + 1.0f);   // 1.1 - ev + es
                num[c] += pv[j][c] * w;
                d1[c]  += pv[j][c] * imp;
                d2[c]  += w;
            }
        }
    }

    // wave (64-lane) shuffle reduce, cross-wave via LDS, per-block slot write
    __shared__ float red[TPB / 64][NACC];
    const int lane = threadIdx.x & 63;
    const int wid = threadIdx.x >> 6;
    float acc[NACC];
#pragma unroll
    for (int k = 0; k < 3; ++k) { acc[k] = num[k]; acc[3 + k] = d1[k]; acc[6 + k] = d2[k]; }
#pragma unroll
    for (int k = 0; k < NACC; ++k) {
        float v = acc[k];
#pragma unroll
        for (int off = 32; off > 0; off >>= 1) v += __shfl_down(v, off, 64);
        if (lane == 0) red[wid][k] = v;
    }
    __syncthreads();
    if (wid == 0 && lane < NACC) {
        float v = 0.f;
#pragma unroll
        for (int w8 = 0; w8 < TPB / 64; ++w8) v += red[w8][lane];
        // slot layout: ws[(b*NACC + k) * GX + bx] -> every slot written every call
        ws[((size_t)(b * NACC + lane)) * GX + bx] = v;
    }
}

__global__ __launch_bounds__(FTPB) void ske_final_kernel(
    const float* __restrict__ ws, float* __restrict__ out)
{
    // 18 rows x GX floats; thread t reads float2 #t of each row (GX==FTPB*2):
    // 18 independent vec loads, one wait, 18 parallel shuffle-reduces.
    float acc[2 * NACC];
#pragma unroll
    for (int s = 0; s < 2 * NACC; ++s) {
        const float2 v = ((const float2*)(ws + (size_t)s * GX))[threadIdx.x];
        acc[s] = v.x + v.y;
    }
    __shared__ float red[4][2 * NACC];
    const int lane = threadIdx.x & 63;
    const int wid = threadIdx.x >> 6;
#pragma unroll
    for (int s = 0; s < 2 * NACC; ++s) {
        float v = acc[s];
#pragma unroll
        for (int off = 32; off > 0; off >>= 1) v += __shfl_down(v, off, 64);
        if (lane == 0) red[wid][s] = v;
    }
    __syncthreads();
    if (threadIdx.x == 0) {
        float tot[2 * NACC];
#pragma unroll
        for (int s = 0; s < 2 * NACC; ++s)
            tot[s] = red[0][s] + red[1][s] + red[2][s] + red[3][s];
        float loss = 0.f;
#pragma unroll
        for (int b = 0; b < 2; ++b) {
            float ssum = 0.f;
#pragma unroll
            for (int c = 0; c < 3; ++c) {
                const float n  = tot[b * NACC + c];
                const float e1 = tot[b * NACC + 3 + c];
                const float e2 = tot[b * NACC + 6 + c];
                ssum += (26.f * n + 1e-4f) / (e1 + 25.f * e2 + 1e-4f);
            }
            loss += ssum * (1.f / 3.f);
        }
        out[0] = -loss * 0.5f;
    }
}

extern "C" void kernel_launch(void* const* d_in, const int* in_sizes, int n_in,
                              void* d_out, int out_size, void* d_ws, size_t ws_size,
                              hipStream_t stream) {
    const float* out_probs = (const float*)d_in[0];
    const int* labels = (const int*)d_in[1];
    float* ws = (float*)d_ws;

    dim3 grid(GX, 2);
    ske_partial_kernel<<<grid, TPB, 0, stream>>>(out_probs, labels, ws);
    ske_final_kernel<<<1, FTPB, 0, stream>>>(ws, (float*)d_out);
}

// Round 8
// 35.882 us; speedup vs baseline: 1.1539x; 1.1539x over previous
//
#include <hip/hip_runtime.h>

// SkeLossMultiClass: streaming reduction, two kernels (partial + final).
// B=2, C=4, D=64, H=256, W=256; classes 1..3; BETA=25, EPS=1e-4.
// Per element, per class c: ev=(v==c), es=(s==c)
//   num_c  += p_c * ev * (0.1+es)
//   den1_c += p_c * (1.1 - ev + es)
//   den2_c += ev * (0.1+es)
// score = (26*num+eps)/(den1+25*den2+eps); loss = -mean_b(sum_c score/3)
// Channel 0 of probs never read (33 MB saved). Ignore-mask is a provable no-op.
// R4 lesson: NO __threadfence() on the hot path (per-thread fences -> 242 us).
// R5 lesson: contiguous 16 KB/stream/block + TPB=256 is the scanned optimum.
// R6 lesson: 32 KB chunks w/ TPB=512 regress (block-shape overhead dominates).
// R7 lesson: __builtin_nontemporal_load needs native vectors, not HIP_vector_type.
// R8: R5 structure + nt loads via clang ext_vector types.

#define DHW (64 * 256 * 256)   // 4194304
#define NVEC (DHW / 4)         // 1048576 float4/int4 per (b,c)
#define GX 1024
#define TPB 256
#define NITER 4
#define CHUNK (TPB * NITER)    // 1024 float4s: contiguous 16 KB per stream/block
#define NACC 9                 // num[3], den1[3], den2[3]

typedef float f32x4 __attribute__((ext_vector_type(4)));
typedef int i32x4 __attribute__((ext_vector_type(4)));

__global__ __launch_bounds__(TPB) void ske_partial_kernel(
    const float* __restrict__ out, const int* __restrict__ labels,
    float* __restrict__ ws)
{
    const int b = blockIdx.y;
    const int bx = blockIdx.x;
    const f32x4* p1 = (const f32x4*)(out + ((size_t)(b * 4 + 1)) * DHW);
    const f32x4* p2 = (const f32x4*)(out + ((size_t)(b * 4 + 2)) * DHW);
    const f32x4* p3 = (const f32x4*)(out + ((size_t)(b * 4 + 3)) * DHW);
    const i32x4* ves = (const i32x4*)(labels + (size_t)(b * 2) * DHW);
    const i32x4* ske = ves + NVEC;

    // Contiguous 16 KB per stream per block; 20 independent nt loads up-front.
    const int base = bx * CHUNK + threadIdx.x;

    f32x4 A1[NITER], A2[NITER], A3[NITER];
    i32x4 V[NITER], S[NITER];
#pragma unroll
    for (int q = 0; q < NITER; ++q) {
        const int i = base + q * TPB;
        A1[q] = __builtin_nontemporal_load(&p1[i]);
        A2[q] = __builtin_nontemporal_load(&p2[i]);
        A3[q] = __builtin_nontemporal_load(&p3[i]);
        V[q] = __builtin_nontemporal_load(&ves[i]);
        S[q] = __builtin_nontemporal_load(&ske[i]);
    }

    float num[3] = {0.f, 0.f, 0.f};
    float d1[3]  = {0.f, 0.f, 0.f};
    float d2[3]  = {0.f, 0.f, 0.f};

#pragma unroll
    for (int q = 0; q < NITER; ++q) {
#pragma unroll
        for (int j = 0; j < 4; ++j) {
            const float pj[3] = {A1[q][j], A2[q][j], A3[q][j]};
            const int vj = V[q][j];
            const int sj = S[q][j];
#pragma unroll
            for (int c = 0; c < 3; ++c) {
                const bool mv = (vj == c + 1);
                const bool ms = (sj == c + 1);
                const float t   = ms ? 1.1f : 0.1f;      // 0.1 + es
                const float w   = mv ? t : 0.0f;         // ev*(0.1+es)
                const float imp = mv ? t : (t + 1.0f);   // 1.1 - ev + es
                num[c] += pj[c] * w;
                d1[c]  += pj[c] * imp;
                d2[c]  += w;
            }
        }
    }

    // wave (64-lane) shuffle reduce, cross-wave via LDS, per-block slot write
    __shared__ float red[4][NACC];
    const int lane = threadIdx.x & 63;
    const int wid = threadIdx.x >> 6;
    float acc[NACC];
#pragma unroll
    for (int k = 0; k < 3; ++k) { acc[k] = num[k]; acc[3 + k] = d1[k]; acc[6 + k] = d2[k]; }
#pragma unroll
    for (int k = 0; k < NACC; ++k) {
        float v = acc[k];
#pragma unroll
        for (int off = 32; off > 0; off >>= 1) v += __shfl_down(v, off, 64);
        if (lane == 0) red[wid][k] = v;
    }
    __syncthreads();
    if (wid == 0 && lane < NACC) {
        const float v = red[0][lane] + red[1][lane] + red[2][lane] + red[3][lane];
        // slot layout: ws[(b*NACC + k) * GX + bx] -> every slot written every call
        ws[((size_t)(b * NACC + lane)) * GX + bx] = v;
    }
}

__global__ __launch_bounds__(TPB) void ske_final_kernel(
    const float* __restrict__ ws, float* __restrict__ out)
{
    // 18 rows x GX floats; thread t reads float4 #t of each row (GX==TPB*4):
    // 18 independent vec loads, one wait, 18 parallel shuffle-reduces.
    float acc[2 * NACC];
#pragma unroll
    for (int s = 0; s < 2 * NACC; ++s) {
        const f32x4 v = ((const f32x4*)(ws + (size_t)s * GX))[threadIdx.x];
        acc[s] = (v[0] + v[1]) + (v[2] + v[3]);
    }
    __shared__ float red[4][2 * NACC];
    const int lane = threadIdx.x & 63;
    const int wid = threadIdx.x >> 6;
#pragma unroll
    for (int s = 0; s < 2 * NACC; ++s) {
        float v = acc[s];
#pragma unroll
        for (int off = 32; off > 0; off >>= 1) v += __shfl_down(v, off, 64);
        if (lane == 0) red[wid][s] = v;
    }
    __syncthreads();
    if (threadIdx.x == 0) {
        float tot[2 * NACC];
#pragma unroll
        for (int s = 0; s < 2 * NACC; ++s)
            tot[s] = red[0][s] + red[1][s] + red[2][s] + red[3][s];
        float loss = 0.f;
#pragma unroll
        for (int b = 0; b < 2; ++b) {
            float ssum = 0.f;
#pragma unroll
            for (int c = 0; c < 3; ++c) {
                const float n  = tot[b * NACC + c];
                const float e1 = tot[b * NACC + 3 + c];
                const float e2 = tot[b * NACC + 6 + c];
                ssum += (26.f * n + 1e-4f) / (e1 + 25.f * e2 + 1e-4f);
            }
            loss += ssum * (1.f / 3.f);
        }
        out[0] = -loss * 0.5f;
    }
}

extern "C" void kernel_launch(void* const* d_in, const int* in_sizes, int n_in,
                              void* d_out, int out_size, void* d_ws, size_t ws_size,
                              hipStream_t stream) {
    const float* out_probs = (const float*)d_in[0];
    const int* labels = (const int*)d_in[1];
    float* ws = (float*)d_ws;

    dim3 grid(GX, 2);
    ske_partial_kernel<<<grid, TPB, 0, stream>>>(out_probs, labels, ws);
    ske_final_kernel<<<1, TPB, 0, stream>>>(ws, (float*)d_out);
}